// Round 11
// baseline (127.849 us; speedup 1.0000x reference)
//
#include <hip/hip_runtime.h>
#include <hip/hip_bf16.h>
#include <math.h>

typedef __attribute__((ext_vector_type(4))) float floatx4;
typedef __attribute__((ext_vector_type(8))) __bf16 bf16x8;

#define B_ROWS 4096
#define D_DIM  1024
#define C_CUR  1000
#define P_PREV 2000
#define C_PAD  1024
#define P_PAD  2048
#define N_TOT  (C_PAD + P_PAD)   // 3072

// NOTE: __builtin_amdgcn_global_load_lds is BANNED this session: 4/4 container
// deaths (R4-R6 per-lane dst, R8 wave-uniform dst) vs clean runs without.
// Barrier that does NOT drain vmcnt (prefetch loads stay in flight); manual
// lgkmcnt(0) gives cross-wave LDS visibility. "memory" clobber pins ordering.
#define LDS_BARRIER() asm volatile("s_waitcnt lgkmcnt(0)\n\ts_barrier" ::: "memory")

__device__ __forceinline__ float wave_sum(float v) {
#pragma unroll
  for (int o = 32; o > 0; o >>= 1) v += __shfl_xor(v, o, 64);
  return v;
}
__device__ __forceinline__ float wave_max(float v) {
#pragma unroll
  for (int o = 32; o > 0; o >>= 1) v = fmaxf(v, __shfl_xor(v, o, 64));
  return v;
}

// ---------------------------------------------------------------------------
// Fused L2-normalize: one WAVE per row. rows 0..4095 = features -> fn,
// 4096..5119 = cur_proto -> proto[0..1024), 5120..7167 = prev_proto ->
// proto[1024..3072). Pad rows zero-filled. No LDS, no barriers.
// ---------------------------------------------------------------------------
__global__ __launch_bounds__(256) void norm_all_kernel(
    const float* __restrict__ features, const float* __restrict__ cur_proto,
    const float* __restrict__ prev_proto, __hip_bfloat16* __restrict__ fn,
    __hip_bfloat16* __restrict__ proto) {
  const int wv = threadIdx.x >> 6, lane = threadIdx.x & 63;
  const int r = blockIdx.x * 4 + wv;
  const float* src;
  unsigned short* dst;
  bool valid;
  if (r < B_ROWS) {
    src = features + (size_t)r * D_DIM;
    dst = (unsigned short*)fn + (size_t)r * D_DIM;
    valid = true;
  } else if (r < B_ROWS + C_PAD) {
    const int rr = r - B_ROWS;
    src = cur_proto + (size_t)rr * D_DIM;
    dst = (unsigned short*)proto + (size_t)rr * D_DIM;
    valid = rr < C_CUR;
  } else {
    const int rr = r - B_ROWS - C_PAD;
    src = prev_proto + (size_t)rr * D_DIM;
    dst = (unsigned short*)proto + (size_t)(C_PAD + rr) * D_DIM;
    valid = rr < P_PREV;
  }
  if (!valid) {
    ushort4 z = {0, 0, 0, 0};
#pragma unroll
    for (int k = 0; k < 4; ++k) *(ushort4*)(dst + lane * 4 + k * 256) = z;
    return;
  }
  float4 v[4];
  float ss = 0.f;
#pragma unroll
  for (int k = 0; k < 4; ++k) {
    v[k] = *(const float4*)(src + lane * 4 + k * 256);
    ss += v[k].x * v[k].x + v[k].y * v[k].y + v[k].z * v[k].z + v[k].w * v[k].w;
  }
  ss = wave_sum(ss);
  const float inv = 1.0f / fmaxf(sqrtf(ss), 1e-12f);
#pragma unroll
  for (int k = 0; k < 4; ++k) {
    __hip_bfloat16 h0 = __float2bfloat16(v[k].x * inv);
    __hip_bfloat16 h1 = __float2bfloat16(v[k].y * inv);
    __hip_bfloat16 h2 = __float2bfloat16(v[k].z * inv);
    __hip_bfloat16 h3 = __float2bfloat16(v[k].w * inv);
    ushort4 u;
    u.x = *(unsigned short*)&h0;
    u.y = *(unsigned short*)&h1;
    u.z = *(unsigned short*)&h2;
    u.w = *(unsigned short*)&h3;
    *(ushort4*)(dst + lane * 4 + k * 256) = u;
  }
}

// ---------------------------------------------------------------------------
// GEMM: C[M][N] = A[M][K]*B[N][K]^T, bf16 in/out, fp32 accum.
// 128x128 tile, BK=32. UNPADDED [128][32] LDS (m97/m98 layout: 519
// conflict-cyc/block measured vs 8190 for the padded LSTR=40 variant).
// Staging: thread (w,lane) owns 16B chunks q=w*64+lane and q+256; a wave's
// ds_write_b128 lands 64 contiguous 16B pieces (stride 16B = GLD16 pattern).
// Double-buffered + register prefetch + lgkm-only s_barrier (R10).
// C/D map (m89/m91): row=(lane>>4)*4+reg, col=lane&15.
// ---------------------------------------------------------------------------
#define TM    128
#define BK    32
#define KITER (D_DIM / BK)  // 32

__global__ __launch_bounds__(256) void gemm_bf16_kernel(
    const __hip_bfloat16* __restrict__ A,
    const __hip_bfloat16* __restrict__ Bm,
    __hip_bfloat16* __restrict__ Cm) {
  __shared__ alignas(16) unsigned short lA[2][TM * BK];  // 2 x 8 KB
  __shared__ alignas(16) unsigned short lB[2][TM * BK];  // 2 x 8 KB
  const int t = threadIdx.x;
  const int bm = blockIdx.y, bn = blockIdx.x;
  const unsigned short* Ag = (const unsigned short*)A + (size_t)bm * TM * D_DIM;
  const unsigned short* Bg = (const unsigned short*)Bm + (size_t)bn * TM * D_DIM;

  const int lane = t & 63, wv = t >> 6;
  const int wm = (wv >> 1) * 64, wn = (wv & 1) * 64;
  const int quad = lane >> 4, l16 = lane & 15;

  // staging: chunk qa = wv*64+lane -> row qa>>2 = wv*16+(lane>>2),
  // k-off (lane&3)*8; chunk qb = qa+256 -> row +64, same k-off.
  const int qa = wv * 64 + lane;
  const int row_a = qa >> 2, ko = (lane & 3) * 8;
  const unsigned short* a0p = Ag + (size_t)row_a * D_DIM + ko;
  const unsigned short* a1p = Ag + (size_t)(row_a + 64) * D_DIM + ko;
  const unsigned short* b0p = Bg + (size_t)row_a * D_DIM + ko;
  const unsigned short* b1p = Bg + (size_t)(row_a + 64) * D_DIM + ko;
  const int wr0 = qa * 8;           // short offset of chunk qa
  const int wr1 = qa * 8 + 2048;    // chunk qa+256

  floatx4 acc[4][4] = {};

  // prologue: tile 0 -> buf0; issue tile 1 loads; barrier (no vmcnt drain)
  float4 a0 = *(const float4*)(a0p);
  float4 a1 = *(const float4*)(a1p);
  float4 b0 = *(const float4*)(b0p);
  float4 b1 = *(const float4*)(b1p);
  *(float4*)(lA[0] + wr0) = a0;
  *(float4*)(lA[0] + wr1) = a1;
  *(float4*)(lB[0] + wr0) = b0;
  *(float4*)(lB[0] + wr1) = b1;
  a0 = *(const float4*)(a0p + BK);
  a1 = *(const float4*)(a1p + BK);
  b0 = *(const float4*)(b0p + BK);
  b1 = *(const float4*)(b1p + BK);
  LDS_BARRIER();

#pragma unroll 2
  for (int i = 0; i < KITER; ++i) {
    const int p = i & 1;
    if (i < KITER - 1) {
      // tile i+1 (in regs, loaded a full iteration ago) -> buf[1-p]
      *(float4*)(lA[1 - p] + wr0) = a0;
      *(float4*)(lA[1 - p] + wr1) = a1;
      *(float4*)(lB[1 - p] + wr0) = b0;
      *(float4*)(lB[1 - p] + wr1) = b1;
      // issue tile i+2 loads (clamped; last-1 iter re-reads, harmless)
      const int nk = (i + 2 < KITER) ? (i + 2) * BK : (KITER - 1) * BK;
      a0 = *(const float4*)(a0p + nk);
      a1 = *(const float4*)(a1p + nk);
      b0 = *(const float4*)(b0p + nk);
      b1 = *(const float4*)(b1p + nk);
    }
    // compute from buf[p]
    bf16x8 af[4], bfr[4];
#pragma unroll
    for (int x = 0; x < 4; ++x)
      af[x] = *(const bf16x8*)(lA[p] + (wm + x * 16 + l16) * BK + quad * 8);
#pragma unroll
    for (int y = 0; y < 4; ++y)
      bfr[y] = *(const bf16x8*)(lB[p] + (wn + y * 16 + l16) * BK + quad * 8);
#pragma unroll
    for (int x = 0; x < 4; ++x)
#pragma unroll
      for (int y = 0; y < 4; ++y)
        acc[x][y] = __builtin_amdgcn_mfma_f32_16x16x32_bf16(af[x], bfr[y], acc[x][y], 0, 0, 0);
    LDS_BARRIER();  // writes to buf[1-p] visible; all reads of buf[p] done
  }

  unsigned short* Cu = (unsigned short*)Cm;
#pragma unroll
  for (int x = 0; x < 4; ++x)
#pragma unroll
    for (int y = 0; y < 4; ++y)
#pragma unroll
      for (int r = 0; r < 4; ++r) {
        const int row = bm * TM + wm + x * 16 + quad * 4 + r;
        const int col = bn * TM + wn + y * 16 + l16;
        __hip_bfloat16 h = __float2bfloat16(acc[x][y][r]);
        Cu[(size_t)row * N_TOT + col] = *(unsigned short*)&h;
      }
}

// ---------------------------------------------------------------------------
// One WAVE per row, single-pass: values held in registers (16 intra + 32
// cross floats/lane), bf16x8 loads, ppl mask as bitfield. No barriers.
// ---------------------------------------------------------------------------
__global__ __launch_bounds__(256) void row_reduce_kernel(
    const __hip_bfloat16* __restrict__ sims, const int* __restrict__ labels,
    const int* __restrict__ ppl,
    float* __restrict__ pos_o, float* __restrict__ inf_o, float* __restrict__ crs_o) {
  const int wv = threadIdx.x >> 6, lane = threadIdx.x & 63;
  const int b = blockIdx.x * 4 + wv;
  const unsigned short* row = (const unsigned short*)sims + (size_t)b * N_TOT;
  const int lab = labels[b];

  // ---- intra: cols [0, 1000); cols [1000,1024) are exact zeros (pad), masked
  {
    const int i1 = 512 + lane * 8;
    float vi[16];
    bf16x8 u0 = *(const bf16x8*)(row + lane * 8);
    bf16x8 u1 = *(const bf16x8*)(row + i1);
#pragma unroll
    for (int j = 0; j < 8; ++j) { vi[j] = (float)u0[j]; vi[8 + j] = (float)u1[j]; }
    float sum = 0.f, sq = 0.f, mx = -1e30f;
#pragma unroll
    for (int j = 0; j < 8; ++j) {
      float v = vi[j];
      sum += v; sq += v * v; mx = fmaxf(mx, v);  // lane*8+j < 512 < 1000 always
    }
#pragma unroll
    for (int j = 0; j < 8; ++j) {
      if (i1 + j < C_CUR) { float v = vi[8 + j]; sum += v; sq += v * v; mx = fmaxf(mx, v); }
    }
    sum = wave_sum(sum); sq = wave_sum(sq); mx = wave_max(mx);
    const float var = (sq - sum * sum / (float)C_CUR) / (float)(C_CUR - 1);
    const float sd = sqrtf(fmaxf(var, 0.f));
    const float temp = fminf(fmaxf(0.07f * (1.f + sd), 0.01f), 0.5f);
    const float it = 1.f / temp;
    float se = 0.f;
#pragma unroll
    for (int j = 0; j < 8; ++j) se += __expf((vi[j] - mx) * it);
#pragma unroll
    for (int j = 0; j < 8; ++j)
      if (i1 + j < C_CUR) se += __expf((vi[8 + j] - mx) * it);
    se = wave_sum(se);
    if (lane == 0) {
      __hip_bfloat16 hs;
      *(unsigned short*)&hs = row[lab];
      const float slab = __bfloat162float(hs);
      pos_o[b] = 1.f - slab;
      inf_o[b] = mx * it + logf(se) - slab * it;
    }
  }

  // ---- cross: cols [1024, 3072) = prev protos 0..2047 (2000 valid + pad) ----
  {
    const unsigned short* crow = row + C_PAD;
    float vc[32];
    unsigned mask = 0;
    float sum = 0.f, sq = 0.f, mx = -1e30f;
    int cnt = 0;
#pragma unroll
    for (int k = 0; k < 4; ++k) {
      const int base = k * 512 + lane * 8;
      bf16x8 u = *(const bf16x8*)(crow + base);
#pragma unroll
      for (int j = 0; j < 8; ++j) vc[k * 8 + j] = (float)u[j];
      if (base < P_PREV) {  // base multiple of 8, so base<2000 => base+8<=2000
        int4 p0 = *(const int4*)(ppl + base);
        int4 p1 = *(const int4*)(ppl + base + 4);
        const int pl[8] = {p0.x, p0.y, p0.z, p0.w, p1.x, p1.y, p1.z, p1.w};
#pragma unroll
        for (int j = 0; j < 8; ++j) {
          if (pl[j] != lab) {
            mask |= 1u << (k * 8 + j);
            float v = vc[k * 8 + j];
            sum += v; sq += v * v; mx = fmaxf(mx, v); ++cnt;
          }
        }
      }
    }
    sum = wave_sum(sum); sq = wave_sum(sq); mx = wave_max(mx);
    const float n = wave_sum((float)cnt);
    const float var = (sq - sum * sum / n) / (n - 1.f);
    const float sd = sqrtf(fmaxf(var, 0.f));
    const float ct = 2.f * fminf(fmaxf(0.07f * (1.f + sd), 0.01f), 0.5f);
    const float it = 1.f / ct;
    float se = 0.f;
#pragma unroll
    for (int e = 0; e < 32; ++e)
      if ((mask >> e) & 1u) se += __expf((vc[e] - mx) * it);
    se = wave_sum(se);
    if (lane == 0) crs_o[b] = mx * it + logf(se);
  }
}

// ---------------------------------------------------------------------------
__global__ __launch_bounds__(1024) void final_reduce_kernel(
    const float* __restrict__ pos_o, const float* __restrict__ inf_o,
    const float* __restrict__ crs_o, float* __restrict__ out) {
  const int t = threadIdx.x;
  __shared__ float sA[1024], sB[1024], sC[1024];
  float a = 0.f, bb = 0.f, c = 0.f;
  for (int i = t; i < B_ROWS; i += 1024) {
    a += pos_o[i]; bb += inf_o[i]; c += crs_o[i];
  }
  sA[t] = a; sB[t] = bb; sC[t] = c;
  __syncthreads();
  for (int o = 512; o > 0; o >>= 1) {
    if (t < o) { sA[t] += sA[t + o]; sB[t] += sB[t + o]; sC[t] += sC[t + o]; }
    __syncthreads();
  }
  if (t == 0) {
    const float invB = 1.f / (float)B_ROWS;
    const float pos = sA[0] * invB;
    const float neg = sB[0] * invB + 0.3f * sC[0] * invB;
    const float curr_beta = 0.5f * (0.1f + 0.9f * (1.0f / 1000.0f));  // step=1/warmup=1000
    out[0] = pos + curr_beta * neg;                                   // ALPHA=1
  }
}

// ---------------------------------------------------------------------------
extern "C" void kernel_launch(void* const* d_in, const int* in_sizes, int n_in,
                              void* d_out, int out_size, void* d_ws, size_t ws_size,
                              hipStream_t stream) {
  const float* features   = (const float*)d_in[0];
  const float* cur_proto  = (const float*)d_in[1];
  const float* prev_proto = (const float*)d_in[2];
  const int*   labels     = (const int*)d_in[3];
  const int*   ppl        = (const int*)d_in[4];

  char* w = (char*)d_ws;
  __hip_bfloat16* fn    = (__hip_bfloat16*)w;                                  // 8 MB
  __hip_bfloat16* proto = (__hip_bfloat16*)(w + (size_t)8 * 1024 * 1024);      // 6 MB
  __hip_bfloat16* sims  = (__hip_bfloat16*)(w + (size_t)14 * 1024 * 1024);     // 24 MB
  char* tail = w + (size_t)14 * 1024 * 1024 + (size_t)B_ROWS * N_TOT * 2;
  float* pos_o = (float*)tail;
  float* inf_o = pos_o + B_ROWS;
  float* crs_o = inf_o + B_ROWS;

  norm_all_kernel<<<(B_ROWS + C_PAD + P_PAD) / 4, 256, 0, stream>>>(
      features, cur_proto, prev_proto, fn, proto);

  dim3 grid(N_TOT / TM, B_ROWS / TM);
  gemm_bf16_kernel<<<grid, 256, 0, stream>>>(fn, proto, sims);

  row_reduce_kernel<<<B_ROWS / 4, 256, 0, stream>>>(sims, labels, ppl, pos_o, inf_o, crs_o);
  final_reduce_kernel<<<1, 1024, 0, stream>>>(pos_o, inf_o, crs_o, (float*)d_out);
}

// Round 12
// 122.960 us; speedup vs baseline: 1.0398x; 1.0398x over previous
//
#include <hip/hip_runtime.h>
#include <hip/hip_bf16.h>
#include <math.h>

typedef __attribute__((ext_vector_type(4))) float floatx4;
typedef __attribute__((ext_vector_type(8))) __bf16 bf16x8;

#define B_ROWS 4096
#define D_DIM  1024
#define C_CUR  1000
#define P_PREV 2000
#define C_PAD  1024
#define P_PAD  2048
#define N_TOT  (C_PAD + P_PAD)   // 3072

// NOTE: __builtin_amdgcn_global_load_lds is BANNED this session: 4/4 container
// deaths (R4-R6, R8) vs clean runs without.
// Barrier without vmcnt drain (prefetch loads stay in flight).
#define LDS_BARRIER() asm volatile("s_waitcnt lgkmcnt(0)\n\ts_barrier" ::: "memory")

__device__ __forceinline__ float wave_sum(float v) {
#pragma unroll
  for (int o = 32; o > 0; o >>= 1) v += __shfl_xor(v, o, 64);
  return v;
}
__device__ __forceinline__ float wave_max(float v) {
#pragma unroll
  for (int o = 32; o > 0; o >>= 1) v = fmaxf(v, __shfl_xor(v, o, 64));
  return v;
}

// float -> OCP e4m3fn, RNE, manual (values here are |x| <= 1, no NaN/inf).
__device__ __forceinline__ unsigned char f32_to_e4m3(float x) {
  unsigned u = __float_as_uint(x);
  unsigned s = (u >> 24) & 0x80u;
  float a = fabsf(x);
  if (a < 0.015625f) {                    // subnormal: step 2^-9
    int q = (int)rintf(a * 512.0f);       // 0..8; 8 rolls into exp=1,m=0 (2^-6)
    return (unsigned char)(s | (unsigned)q);
  }
  unsigned au = u & 0x7fffffffu;
  unsigned r = au + 0x0007ffffu + ((au >> 20) & 1u);  // RNE at bit 20
  int e = (int)(r >> 23) - 127;
  unsigned m = (r >> 20) & 7u;
  return (unsigned char)(s | ((unsigned)(e + 7) << 3) | m);
}

// ---------------------------------------------------------------------------
// Fused L2-normalize -> fp8 e4m3. One WAVE per row; lane owns 16 contiguous
// elements (bytes lane*16.. in output). Pad rows zero-filled.
// ---------------------------------------------------------------------------
__global__ __launch_bounds__(256) void norm_all_kernel(
    const float* __restrict__ features, const float* __restrict__ cur_proto,
    const float* __restrict__ prev_proto, unsigned char* __restrict__ fn,
    unsigned char* __restrict__ proto) {
  const int wv = threadIdx.x >> 6, lane = threadIdx.x & 63;
  const int r = blockIdx.x * 4 + wv;
  const float* src;
  unsigned char* dst;
  bool valid;
  if (r < B_ROWS) {
    src = features + (size_t)r * D_DIM;
    dst = fn + (size_t)r * D_DIM;
    valid = true;
  } else if (r < B_ROWS + C_PAD) {
    const int rr = r - B_ROWS;
    src = cur_proto + (size_t)rr * D_DIM;
    dst = proto + (size_t)rr * D_DIM;
    valid = rr < C_CUR;
  } else {
    const int rr = r - B_ROWS - C_PAD;
    src = prev_proto + (size_t)rr * D_DIM;
    dst = proto + (size_t)(C_PAD + rr) * D_DIM;
    valid = rr < P_PREV;
  }
  if (!valid) {
    uint4 z = {0, 0, 0, 0};
    *(uint4*)(dst + lane * 16) = z;
    return;
  }
  float4 v[4];
  float ss = 0.f;
#pragma unroll
  for (int k = 0; k < 4; ++k) {
    v[k] = *(const float4*)(src + lane * 16 + k * 4);  // 16 contiguous elems
    ss += v[k].x * v[k].x + v[k].y * v[k].y + v[k].z * v[k].z + v[k].w * v[k].w;
  }
  ss = wave_sum(ss);
  const float inv = 1.0f / fmaxf(sqrtf(ss), 1e-12f);
  union { unsigned char b[16]; uint4 q; } o;
#pragma unroll
  for (int k = 0; k < 4; ++k) {
    o.b[k * 4 + 0] = f32_to_e4m3(v[k].x * inv);
    o.b[k * 4 + 1] = f32_to_e4m3(v[k].y * inv);
    o.b[k * 4 + 2] = f32_to_e4m3(v[k].z * inv);
    o.b[k * 4 + 3] = f32_to_e4m3(v[k].w * inv);
  }
  *(uint4*)(dst + lane * 16) = o.q;
}

// ---------------------------------------------------------------------------
// GEMM fp8: C[M][N] = A[M][K]*B[N][K]^T, fp8 e4m3 in, bf16 out, fp32 accum.
// 128x128 tile, BK=32 (32 B/row). LDS row stride 48 B (16 B pad: reads ~2-way
// free). Double-buffered + register prefetch + lgkm-only s_barrier (R10).
// mfma_f32_16x16x32_fp8_fp8: A/B frag = 8 fp8 = 8 B/lane (ds_read_b64),
// k = quad*8..+8, row/col = lane&15 -- byte analog of the bf16 mapping.
// C/D map (m89/m91): row=(lane>>4)*4+reg, col=lane&15.
// ---------------------------------------------------------------------------
#define TM    128
#define BK    32
#define LSTRB 48                 // bytes per LDS row: 32 + 16 pad
#define KITER (D_DIM / BK)       // 32

__global__ __launch_bounds__(256) void gemm_fp8_kernel(
    const unsigned char* __restrict__ A,
    const unsigned char* __restrict__ Bm,
    __hip_bfloat16* __restrict__ Cm) {
  __shared__ alignas(16) unsigned char lA[2][TM * LSTRB];  // 2 x 6 KB
  __shared__ alignas(16) unsigned char lB[2][TM * LSTRB];  // 2 x 6 KB
  const int t = threadIdx.x;
  const int bm = blockIdx.y, bn = blockIdx.x;
  const unsigned char* Ag = A + (size_t)bm * TM * D_DIM;
  const unsigned char* Bg = Bm + (size_t)bn * TM * D_DIM;

  const int lane = t & 63, wv = t >> 6;
  const int wm = (wv >> 1) * 64, wn = (wv & 1) * 64;
  const int quad = lane >> 4, l16 = lane & 15;

  // staging: 256 16B chunks per matrix per tile = 1 per thread.
  // thread t: row = t>>1, half = t&1 (16 B offset).
  const int srow = t >> 1, shalf = (t & 1) * 16;
  const unsigned char* ap = Ag + (size_t)srow * D_DIM + shalf;
  const unsigned char* bp = Bg + (size_t)srow * D_DIM + shalf;
  const int wroff = srow * LSTRB + shalf;

  floatx4 acc[4][4] = {};

  // prologue: tile 0 -> buf0; issue tile 1 loads; barrier (no vmcnt drain)
  float4 a0 = *(const float4*)(ap);
  float4 b0 = *(const float4*)(bp);
  *(float4*)(lA[0] + wroff) = a0;
  *(float4*)(lB[0] + wroff) = b0;
  a0 = *(const float4*)(ap + BK);
  b0 = *(const float4*)(bp + BK);
  LDS_BARRIER();

#pragma unroll 2
  for (int i = 0; i < KITER; ++i) {
    const int p = i & 1;
    if (i < KITER - 1) {
      *(float4*)(lA[1 - p] + wroff) = a0;   // tile i+1 -> buf[1-p]
      *(float4*)(lB[1 - p] + wroff) = b0;
      const int nk = (i + 2 < KITER) ? (i + 2) * BK : (KITER - 1) * BK;
      a0 = *(const float4*)(ap + nk);       // issue tile i+2 loads
      b0 = *(const float4*)(bp + nk);
    }
    long long af[4], bfr[4];
#pragma unroll
    for (int x = 0; x < 4; ++x)
      af[x] = *(const long long*)(lA[p] + (wm + x * 16 + l16) * LSTRB + quad * 8);
#pragma unroll
    for (int y = 0; y < 4; ++y)
      bfr[y] = *(const long long*)(lB[p] + (wn + y * 16 + l16) * LSTRB + quad * 8);
#pragma unroll
    for (int x = 0; x < 4; ++x)
#pragma unroll
      for (int y = 0; y < 4; ++y)
        acc[x][y] = __builtin_amdgcn_mfma_f32_16x16x32_fp8_fp8(af[x], bfr[y], acc[x][y], 0, 0, 0);
    LDS_BARRIER();
  }

  unsigned short* Cu = (unsigned short*)Cm;
#pragma unroll
  for (int x = 0; x < 4; ++x)
#pragma unroll
    for (int y = 0; y < 4; ++y)
#pragma unroll
      for (int r = 0; r < 4; ++r) {
        const int row = bm * TM + wm + x * 16 + quad * 4 + r;
        const int col = bn * TM + wn + y * 16 + l16;
        __hip_bfloat16 h = __float2bfloat16(acc[x][y][r]);
        Cu[(size_t)row * N_TOT + col] = *(unsigned short*)&h;
      }
}

// ---------------------------------------------------------------------------
// One WAVE per row, single-pass reductions (unchanged from R10).
// ---------------------------------------------------------------------------
__global__ __launch_bounds__(256) void row_reduce_kernel(
    const __hip_bfloat16* __restrict__ sims, const int* __restrict__ labels,
    const int* __restrict__ ppl,
    float* __restrict__ pos_o, float* __restrict__ inf_o, float* __restrict__ crs_o) {
  const int wv = threadIdx.x >> 6, lane = threadIdx.x & 63;
  const int b = blockIdx.x * 4 + wv;
  const unsigned short* row = (const unsigned short*)sims + (size_t)b * N_TOT;
  const int lab = labels[b];

  // ---- intra: cols [0, 1000); [1000,1024) are exact zeros (pad), masked ----
  {
    const int i1 = 512 + lane * 8;
    float vi[16];
    bf16x8 u0 = *(const bf16x8*)(row + lane * 8);
    bf16x8 u1 = *(const bf16x8*)(row + i1);
#pragma unroll
    for (int j = 0; j < 8; ++j) { vi[j] = (float)u0[j]; vi[8 + j] = (float)u1[j]; }
    float sum = 0.f, sq = 0.f, mx = -1e30f;
#pragma unroll
    for (int j = 0; j < 8; ++j) {
      float v = vi[j];
      sum += v; sq += v * v; mx = fmaxf(mx, v);
    }
#pragma unroll
    for (int j = 0; j < 8; ++j) {
      if (i1 + j < C_CUR) { float v = vi[8 + j]; sum += v; sq += v * v; mx = fmaxf(mx, v); }
    }
    sum = wave_sum(sum); sq = wave_sum(sq); mx = wave_max(mx);
    const float var = (sq - sum * sum / (float)C_CUR) / (float)(C_CUR - 1);
    const float sd = sqrtf(fmaxf(var, 0.f));
    const float temp = fminf(fmaxf(0.07f * (1.f + sd), 0.01f), 0.5f);
    const float it = 1.f / temp;
    float se = 0.f;
#pragma unroll
    for (int j = 0; j < 8; ++j) se += __expf((vi[j] - mx) * it);
#pragma unroll
    for (int j = 0; j < 8; ++j)
      if (i1 + j < C_CUR) se += __expf((vi[8 + j] - mx) * it);
    se = wave_sum(se);
    if (lane == 0) {
      __hip_bfloat16 hs;
      *(unsigned short*)&hs = row[lab];
      const float slab = __bfloat162float(hs);
      pos_o[b] = 1.f - slab;
      inf_o[b] = mx * it + logf(se) - slab * it;
    }
  }

  // ---- cross: cols [1024, 3072), masked by ppl != lab ----
  {
    const unsigned short* crow = row + C_PAD;
    float vc[32];
    unsigned mask = 0;
    float sum = 0.f, sq = 0.f, mx = -1e30f;
    int cnt = 0;
#pragma unroll
    for (int k = 0; k < 4; ++k) {
      const int base = k * 512 + lane * 8;
      bf16x8 u = *(const bf16x8*)(crow + base);
#pragma unroll
      for (int j = 0; j < 8; ++j) vc[k * 8 + j] = (float)u[j];
      if (base < P_PREV) {
        int4 p0 = *(const int4*)(ppl + base);
        int4 p1 = *(const int4*)(ppl + base + 4);
        const int pl[8] = {p0.x, p0.y, p0.z, p0.w, p1.x, p1.y, p1.z, p1.w};
#pragma unroll
        for (int j = 0; j < 8; ++j) {
          if (pl[j] != lab) {
            mask |= 1u << (k * 8 + j);
            float v = vc[k * 8 + j];
            sum += v; sq += v * v; mx = fmaxf(mx, v); ++cnt;
          }
        }
      }
    }
    sum = wave_sum(sum); sq = wave_sum(sq); mx = wave_max(mx);
    const float n = wave_sum((float)cnt);
    const float var = (sq - sum * sum / n) / (n - 1.f);
    const float sd = sqrtf(fmaxf(var, 0.f));
    const float ct = 2.f * fminf(fmaxf(0.07f * (1.f + sd), 0.01f), 0.5f);
    const float it = 1.f / ct;
    float se = 0.f;
#pragma unroll
    for (int e = 0; e < 32; ++e)
      if ((mask >> e) & 1u) se += __expf((vc[e] - mx) * it);
    se = wave_sum(se);
    if (lane == 0) crs_o[b] = mx * it + logf(se);
  }
}

// ---------------------------------------------------------------------------
__global__ __launch_bounds__(1024) void final_reduce_kernel(
    const float* __restrict__ pos_o, const float* __restrict__ inf_o,
    const float* __restrict__ crs_o, float* __restrict__ out) {
  const int t = threadIdx.x;
  __shared__ float sA[1024], sB[1024], sC[1024];
  float a = 0.f, bb = 0.f, c = 0.f;
  for (int i = t; i < B_ROWS; i += 1024) {
    a += pos_o[i]; bb += inf_o[i]; c += crs_o[i];
  }
  sA[t] = a; sB[t] = bb; sC[t] = c;
  __syncthreads();
  for (int o = 512; o > 0; o >>= 1) {
    if (t < o) { sA[t] += sA[t + o]; sB[t] += sB[t + o]; sC[t] += sC[t + o]; }
    __syncthreads();
  }
  if (t == 0) {
    const float invB = 1.f / (float)B_ROWS;
    const float pos = sA[0] * invB;
    const float neg = sB[0] * invB + 0.3f * sC[0] * invB;
    const float curr_beta = 0.5f * (0.1f + 0.9f * (1.0f / 1000.0f));  // step=1/warmup=1000
    out[0] = pos + curr_beta * neg;                                   // ALPHA=1
  }
}

// ---------------------------------------------------------------------------
extern "C" void kernel_launch(void* const* d_in, const int* in_sizes, int n_in,
                              void* d_out, int out_size, void* d_ws, size_t ws_size,
                              hipStream_t stream) {
  const float* features   = (const float*)d_in[0];
  const float* cur_proto  = (const float*)d_in[1];
  const float* prev_proto = (const float*)d_in[2];
  const int*   labels     = (const int*)d_in[3];
  const int*   ppl        = (const int*)d_in[4];

  char* w = (char*)d_ws;
  unsigned char* fn    = (unsigned char*)w;                                 // 4 MB
  unsigned char* proto = (unsigned char*)(w + (size_t)4 * 1024 * 1024);     // 3 MB
  __hip_bfloat16* sims = (__hip_bfloat16*)(w + (size_t)8 * 1024 * 1024);    // 24 MB
  char* tail = w + (size_t)8 * 1024 * 1024 + (size_t)B_ROWS * N_TOT * 2;
  float* pos_o = (float*)tail;
  float* inf_o = pos_o + B_ROWS;
  float* crs_o = inf_o + B_ROWS;

  norm_all_kernel<<<(B_ROWS + C_PAD + P_PAD) / 4, 256, 0, stream>>>(
      features, cur_proto, prev_proto, fn, proto);

  dim3 grid(N_TOT / TM, B_ROWS / TM);
  gemm_fp8_kernel<<<grid, 256, 0, stream>>>(fn, proto, sims);

  row_reduce_kernel<<<B_ROWS / 4, 256, 0, stream>>>(sims, labels, ppl, pos_o, inf_o, crs_o);
  final_reduce_kernel<<<1, 1024, 0, stream>>>(pos_o, inf_o, crs_o, (float*)d_out);
}